// Round 2
// 376.658 us; speedup vs baseline: 1.0215x; 1.0215x over previous
//
#include <hip/hip_runtime.h>

typedef _Float16 half8 __attribute__((ext_vector_type(8)));
typedef float floatx4 __attribute__((ext_vector_type(4)));

#define K_ 3
#define N_ 16384
#define M_ 4096
#define D_ 128
#define H_ 64

// workspace layout (bytes)
#define OFF_FXH 0
#define SZ_FXH (K_*N_*H_*2)
#define OFF_FZH (OFF_FXH + SZ_FXH)
#define SZ_FZH (K_*M_*H_*2)
#define OFF_NXS (OFF_FZH + SZ_FZH)
#define SZ_NXS (K_*N_*4)
#define OFF_NZS (OFF_NXS + SZ_NXS)
#define SZ_NZS (K_*M_*4)
#define OFF_W1T (OFF_NZS + SZ_NZS)
#define SZ_W1T (K_*D_*H_*4)
#define OFF_W2T (OFF_W1T + SZ_W1T)
#define SZ_W2T (K_*H_*H_*4)
#define OFF_W3T (OFF_W2T + SZ_W2T)

// ---------------- weight transpose (tiny) ----------------
__global__ void transpose_w(const float* __restrict__ W1,
                            const float* __restrict__ W2,
                            const float* __restrict__ W3,
                            float* __restrict__ W1t,
                            float* __restrict__ W2t,
                            float* __restrict__ W3t) {
  int idx = blockIdx.x * 256 + threadIdx.x;
  if (idx < K_*H_*D_) {   // W1[k][h][d] -> W1t[k][d][h]
    int k = idx / (H_*D_); int r = idx % (H_*D_);
    int h = r / D_; int d = r % D_;
    W1t[k*(D_*H_) + d*H_ + h] = W1[idx];
  }
  if (idx < K_*H_*H_) {   // W2[k][g][h] -> W2t[k][h][g]; same for W3
    int k = idx / (H_*H_); int r = idx % (H_*H_);
    int g = r / H_; int h = r % H_;
    W2t[k*(H_*H_) + h*H_ + g] = W2[idx];
    W3t[k*(H_*H_) + h*H_ + g] = W3[idx];
  }
}

// ---------------- phi: fused 3-layer MLP, fp32, scale + fp16 round + norms ----------------
__device__ __forceinline__ float softplus_f(float x) {
  float p = exp2f(x * 1.44269504089f);
  float r = 0.693147180560f * log2f(1.0f + p);
  return (x > 20.0f) ? x : r;
}

__global__ __launch_bounds__(256) void phi_kernel(
    const float* __restrict__ x, const float* __restrict__ z,
    const float* __restrict__ W1t, const float* __restrict__ b1,
    const float* __restrict__ W2t, const float* __restrict__ b2,
    const float* __restrict__ W3t, const float* __restrict__ b3,
    const float* __restrict__ log_sigma,
    _Float16* __restrict__ fxh, float* __restrict__ nxs,
    _Float16* __restrict__ fzh, float* __restrict__ nzs)
{
  // xbuf pad 132 (= 4 mod 32 dwords): wave64 float4 reads land 8/bank = LDS min
  __shared__ float xbuf[64*132];  // 64 rows x 128 d, coalesced-staged
  __shared__ float hbuf[64*68];   // 64 rows x 64 h, pad to 68
  __shared__ float nred[64*4];

  const int which = blockIdx.z;   // 0 -> x, 1 -> z
  const int nrows = which ? M_ : N_;
  if (blockIdx.x * 64 >= nrows) return;
  const float* __restrict__ src = which ? z : x;
  _Float16* __restrict__ dsth = which ? fzh : fxh;
  float* __restrict__ dstn = which ? nzs : nxs;

  const int t = threadIdx.x;
  const int lane = t & 63;
  const int wv = __builtin_amdgcn_readfirstlane(t >> 6); // wave id, uniform -> scalar weight loads
  const int k = blockIdx.y;
  const int row0 = blockIdx.x * 64;
  const int row = row0 + lane;
  const int h0 = wv * 16;

  const float* __restrict__ w1 = W1t + k*(D_*H_);
  const float* __restrict__ w2 = W2t + k*(H_*H_);
  const float* __restrict__ w3 = W3t + k*(H_*H_);

  // ---- coalesced stage of the 64x128 fp32 input tile (was: per-lane row
  // gather, 64 cache lines per load instr -> 8x L1 tag amplification)
  {
    const float4* __restrict__ gx = (const float4*)(src + (size_t)row0 * D_);
    #pragma unroll
    for (int it = 0; it < 8; it++) {
      int idx = t + it*256;          // 0..2047 float4s; 32 float4 per row
      int r = idx >> 5, c = idx & 31;
      *(float4*)&xbuf[r*132 + c*4] = gx[idx];
    }
  }
  __syncthreads();

  float acc[16];
  // ---- layer 1: D=128 -> 16 outputs of H
  #pragma unroll
  for (int i=0;i<16;i++) acc[i] = b1[k*H_ + h0 + i];
  #pragma unroll 2
  for (int d4=0; d4<D_/4; d4++) {
    float4 xv = *(const float4*)&xbuf[lane*132 + d4*4];
    const float* wd = w1 + d4*4*H_ + h0;
    #pragma unroll
    for (int i=0;i<16;i++) acc[i] = fmaf(xv.x, wd[i], acc[i]);
    #pragma unroll
    for (int i=0;i<16;i++) acc[i] = fmaf(xv.y, wd[H_+i], acc[i]);
    #pragma unroll
    for (int i=0;i<16;i++) acc[i] = fmaf(xv.z, wd[2*H_+i], acc[i]);
    #pragma unroll
    for (int i=0;i<16;i++) acc[i] = fmaf(xv.w, wd[3*H_+i], acc[i]);
  }
  #pragma unroll
  for (int i=0;i<16;i+=4) {
    float4 v;
    v.x = softplus_f(acc[i+0]); v.y = softplus_f(acc[i+1]);
    v.z = softplus_f(acc[i+2]); v.w = softplus_f(acc[i+3]);
    *(float4*)&hbuf[lane*68 + h0 + i] = v;
  }
  __syncthreads();
  // ---- layer 2
  #pragma unroll
  for (int i=0;i<16;i++) acc[i] = b2[k*H_ + h0 + i];
  #pragma unroll 2
  for (int h4=0; h4<H_/4; h4++) {
    float4 hv = *(const float4*)&hbuf[lane*68 + h4*4];
    const float* wd = w2 + h4*4*H_ + h0;
    #pragma unroll
    for (int i=0;i<16;i++) acc[i] = fmaf(hv.x, wd[i], acc[i]);
    #pragma unroll
    for (int i=0;i<16;i++) acc[i] = fmaf(hv.y, wd[H_+i], acc[i]);
    #pragma unroll
    for (int i=0;i<16;i++) acc[i] = fmaf(hv.z, wd[2*H_+i], acc[i]);
    #pragma unroll
    for (int i=0;i<16;i++) acc[i] = fmaf(hv.w, wd[3*H_+i], acc[i]);
  }
  __syncthreads();  // all reads of h1 done
  #pragma unroll
  for (int i=0;i<16;i+=4) {
    float4 v;
    v.x = softplus_f(acc[i+0]); v.y = softplus_f(acc[i+1]);
    v.z = softplus_f(acc[i+2]); v.w = softplus_f(acc[i+3]);
    *(float4*)&hbuf[lane*68 + h0 + i] = v;
  }
  __syncthreads();
  // ---- layer 3 (no activation)
  #pragma unroll
  for (int i=0;i<16;i++) acc[i] = b3[k*H_ + h0 + i];
  #pragma unroll 2
  for (int h4=0; h4<H_/4; h4++) {
    float4 hv = *(const float4*)&hbuf[lane*68 + h4*4];
    const float* wd = w3 + h4*4*H_ + h0;
    #pragma unroll
    for (int i=0;i<16;i++) acc[i] = fmaf(hv.x, wd[i], acc[i]);
    #pragma unroll
    for (int i=0;i<16;i++) acc[i] = fmaf(hv.y, wd[H_+i], acc[i]);
    #pragma unroll
    for (int i=0;i<16;i++) acc[i] = fmaf(hv.z, wd[2*H_+i], acc[i]);
    #pragma unroll
    for (int i=0;i<16;i++) acc[i] = fmaf(hv.w, wd[3*H_+i], acc[i]);
  }
  // ---- scale by sqrt(c2_k), round to fp16, norms from ROUNDED values
  float lsv = log_sigma[k];
  float inv2sig = 0.5f * exp2f(-lsv * 3.32192809489f);  // 1/(2*10^ls)
  float c2 = inv2sig * 1.44269504089f;                  // * log2(e)
  float s = sqrtf(c2);
  half8 u0, u1;
  float nsum = 0.f;
  #pragma unroll
  for (int i=0;i<8;i++) {
    _Float16 v = (_Float16)(s * acc[i]);
    u0[i] = v; float f = (float)v; nsum = fmaf(f, f, nsum);
  }
  #pragma unroll
  for (int i=0;i<8;i++) {
    _Float16 v = (_Float16)(s * acc[8+i]);
    u1[i] = v; float f = (float)v; nsum = fmaf(f, f, nsum);
  }
  _Float16* dp = dsth + ((size_t)k*nrows + row)*H_ + h0;
  *(half8*)dp = u0;
  *(half8*)(dp + 8) = u1;
  nred[lane*4 + wv] = nsum;
  __syncthreads();
  if (t < 64) {
    float v = nred[t*4+0] + nred[t*4+1] + nred[t*4+2] + nred[t*4+3];
    dstn[(size_t)k*nrows + row] = v;
  }
}

// ---------------- main: fused MFMA dot + exp + weighted sum ----------------
// 512 threads (8 waves), per-wave 64x32 output tile -> ~110 VGPR, fits the
// 128-cap from __launch_bounds__(512,4) => 2 blocks/CU = 16 waves/CU (was 8).
__global__ __launch_bounds__(512, 4) void dkef_main(
    const _Float16* __restrict__ fxh, const _Float16* __restrict__ fzh,
    const float* __restrict__ nxs, const float* __restrict__ nzs,
    const float* __restrict__ kw, float* __restrict__ out)
{
  __shared__ __align__(16) _Float16 Ab[128*72];  // 128 n-rows x 64 h, pad 72
  __shared__ __align__(16) _Float16 Bb[128*72];  // 128 m-rows x 64 h
  __shared__ float nxl[128];
  __shared__ float nzl[128];

  const int t = threadIdx.x;
  const int lane = t & 63;
  const int wv = t >> 6;           // 0..7

  // XCD-chunked swizzle: blk->XCD is round-robin on flattened id; give each
  // XCD a contiguous 512-block chunk (16 n-panels x all m-tiles) so its
  // staging working set (fzh 1.5MB + fxh slice 0.8MB) fits the 4MiB L2.
  const int NTM = M_/128;                         // 32
  const int orig = blockIdx.y * NTM + blockIdx.x; // flatten, x fastest
  const int swz = (orig & 7) * ((NTM*(N_/128)) >> 3) + (orig >> 3);
  const int m0 = (swz % NTM) * 128;
  const int n0 = (swz / NTM) * 128;

  // softmax over kernel_weights (3 values), computed redundantly per thread
  float k0 = kw[0], k1 = kw[1], k2 = kw[2];
  float mx = fmaxf(k0, fmaxf(k1, k2));
  float e0 = exp2f((k0 - mx) * 1.44269504089f);
  float e1 = exp2f((k1 - mx) * 1.44269504089f);
  float e2 = exp2f((k2 - mx) * 1.44269504089f);
  float winv = 1.0f / (e0 + e1 + e2);
  float wk3[3] = {e0 * winv, e1 * winv, e2 * winv};

  const int wa = (wv >> 2) * 64;   // n-half within block tile
  const int wb = (wv & 3) * 32;    // m-quarter
  const int fr = lane & 15;        // frag row/col
  const int fq = lane >> 4;        // quad

  floatx4 oacc[4][2] = {};

  for (int k = 0; k < K_; k++) {
    __syncthreads();   // previous iteration done reading LDS
    // stage A (fx rows) and B (fz rows): 16 KB each, int4 chunks, coalesced
    {
      const int4* ga = (const int4*)(fxh + ((size_t)k*N_ + n0)*H_);
      #pragma unroll
      for (int it = 0; it < 2; it++) {
        int idx = t + it*512;
        int r = idx >> 3, c = idx & 7;
        *(int4*)&Ab[r*72 + c*8] = ga[idx];
      }
      const int4* gb = (const int4*)(fzh + ((size_t)k*M_ + m0)*H_);
      #pragma unroll
      for (int it = 0; it < 2; it++) {
        int idx = t + it*512;
        int r = idx >> 3, c = idx & 7;
        *(int4*)&Bb[r*72 + c*8] = gb[idx];
      }
      if (t < 128) nxl[t] = nxs[(size_t)k*N_ + n0 + t];
      else if (t < 256) nzl[t-128] = nzs[(size_t)k*M_ + m0 + (t-128)];
    }
    __syncthreads();

    // MFMA: wave computes 64x32 region = 4x2 tiles of 16x16, K=64 in 2 steps of 32
    floatx4 dacc[4][2] = {};
    #pragma unroll
    for (int ks = 0; ks < 2; ks++) {
      half8 af[4], bf[2];
      #pragma unroll
      for (int i = 0; i < 4; i++)
        af[i] = *(const half8*)&Ab[(wa + i*16 + fr)*72 + ks*32 + fq*8];
      #pragma unroll
      for (int j = 0; j < 2; j++)
        bf[j] = *(const half8*)&Bb[(wb + j*16 + fr)*72 + ks*32 + fq*8];
      #pragma unroll
      for (int i = 0; i < 4; i++)
        #pragma unroll
        for (int j = 0; j < 2; j++)
          dacc[i][j] = __builtin_amdgcn_mfma_f32_16x16x32_f16(af[i], bf[j], dacc[i][j], 0, 0, 0);
    }

    // epilogue: out += w_k * 2^min(2*dot - (nx+nz), 0)
    float wkv = wk3[k];
    #pragma unroll
    for (int i = 0; i < 4; i++) {
      floatx4 nx4 = *(const floatx4*)&nxl[wa + i*16 + fq*4];
      #pragma unroll
      for (int j = 0; j < 2; j++) {
        float nzv = nzl[wb + j*16 + fr];
        #pragma unroll
        for (int r = 0; r < 4; r++) {
          float sm = nx4[r] + nzv;
          float e = fmaf(2.0f, dacc[i][j][r], -sm);
          e = fminf(e, 0.0f);
          oacc[i][j][r] = fmaf(wkv, exp2f(e), oacc[i][j][r]);
        }
      }
    }
  }

  // store 128x128 tile; nontemporal: out is write-once streaming, keep it
  // out of L2 so fxh/fzh staging stays resident.
  #pragma unroll
  for (int i = 0; i < 4; i++) {
    #pragma unroll
    for (int r = 0; r < 4; r++) {
      size_t rowg = (size_t)(n0 + wa + i*16 + fq*4 + r);
      float* orow = out + rowg * M_ + m0 + wb + fr;
      #pragma unroll
      for (int j = 0; j < 2; j++)
        __builtin_nontemporal_store(oacc[i][j][r], &orow[j*16]);
    }
  }
}

extern "C" void kernel_launch(void* const* d_in, const int* in_sizes, int n_in,
                              void* d_out, int out_size, void* d_ws, size_t ws_size,
                              hipStream_t stream) {
  const float* x  = (const float*)d_in[0];
  const float* z  = (const float*)d_in[1];
  const float* W1 = (const float*)d_in[2];
  const float* b1 = (const float*)d_in[3];
  const float* W2 = (const float*)d_in[4];
  const float* b2 = (const float*)d_in[5];
  const float* W3 = (const float*)d_in[6];
  const float* b3 = (const float*)d_in[7];
  const float* ls = (const float*)d_in[8];
  const float* kw = (const float*)d_in[9];
  float* out = (float*)d_out;

  char* ws = (char*)d_ws;
  _Float16* fxh = (_Float16*)(ws + OFF_FXH);
  _Float16* fzh = (_Float16*)(ws + OFF_FZH);
  float* nxs = (float*)(ws + OFF_NXS);
  float* nzs = (float*)(ws + OFF_NZS);
  float* W1t = (float*)(ws + OFF_W1T);
  float* W2t = (float*)(ws + OFF_W2T);
  float* W3t = (float*)(ws + OFF_W3T);

  hipLaunchKernelGGL(transpose_w, dim3((K_*H_*D_ + 255)/256), dim3(256), 0, stream,
                     W1, W2, W3, W1t, W2t, W3t);
  hipLaunchKernelGGL(phi_kernel, dim3(N_/64, K_, 2), dim3(256), 0, stream,
                     x, z, W1t, b1, W2t, b2, W3t, b3, ls, fxh, nxs, fzh, nzs);
  hipLaunchKernelGGL(dkef_main, dim3(M_/128, N_/128), dim3(512), 0, stream,
                     fxh, fzh, nxs, nzs, kw, out);
}

// Round 3
// 357.735 us; speedup vs baseline: 1.0755x; 1.0529x over previous
//
#include <hip/hip_runtime.h>

typedef _Float16 half8 __attribute__((ext_vector_type(8)));
typedef float floatx4 __attribute__((ext_vector_type(4)));

#define K_ 3
#define N_ 16384
#define M_ 4096
#define D_ 128
#define H_ 64

// workspace layout (bytes)
#define OFF_FXH 0
#define SZ_FXH (K_*N_*H_*2)
#define OFF_FZH (OFF_FXH + SZ_FXH)
#define SZ_FZH (K_*M_*H_*2)
#define OFF_NXS (OFF_FZH + SZ_FZH)
#define SZ_NXS (K_*N_*4)
#define OFF_NZS (OFF_NXS + SZ_NXS)
#define SZ_NZS (K_*M_*4)
#define OFF_W1T (OFF_NZS + SZ_NZS)
#define SZ_W1T (K_*D_*H_*4)
#define OFF_W2T (OFF_W1T + SZ_W1T)
#define SZ_W2T (K_*H_*H_*4)
#define OFF_W3T (OFF_W2T + SZ_W2T)

// fxh/fzh are stored FRAGMENT-NATIVE: for each k and 16-row chunk c,
// a 1024-half (2 KB) tile laid out [ks(2)][fq(4)][fr(16)][e(8)] where
// element (row, h) lives at ks=h/32, fq=(h%32)/8, fr=row%16, e=h%8.
// A dkef MFMA fragment load (lane = fq*16+fr... lane&15=fr, lane>>4=fq)
// is then 64 lanes x 16 B = 1024 B CONTIGUOUS -> 8 full cache lines.

// ---------------- weight transpose (tiny) ----------------
__global__ void transpose_w(const float* __restrict__ W1,
                            const float* __restrict__ W2,
                            const float* __restrict__ W3,
                            float* __restrict__ W1t,
                            float* __restrict__ W2t,
                            float* __restrict__ W3t) {
  int idx = blockIdx.x * 256 + threadIdx.x;
  if (idx < K_*H_*D_) {   // W1[k][h][d] -> W1t[k][d][h]
    int k = idx / (H_*D_); int r = idx % (H_*D_);
    int h = r / D_; int d = r % D_;
    W1t[k*(D_*H_) + d*H_ + h] = W1[idx];
  }
  if (idx < K_*H_*H_) {   // W2[k][g][h] -> W2t[k][h][g]; same for W3
    int k = idx / (H_*H_); int r = idx % (H_*H_);
    int g = r / H_; int h = r % H_;
    W2t[k*(H_*H_) + h*H_ + g] = W2[idx];
    W3t[k*(H_*H_) + h*H_ + g] = W3[idx];
  }
}

// ---------------- phi: fused 3-layer MLP, fp32, scale + fp16 round + norms ----------------
__device__ __forceinline__ float softplus_f(float x) {
  float p = exp2f(x * 1.44269504089f);
  float r = 0.693147180560f * log2f(1.0f + p);
  return (x > 20.0f) ? x : r;
}

__global__ __launch_bounds__(256) void phi_kernel(
    const float* __restrict__ x, const float* __restrict__ z,
    const float* __restrict__ W1t, const float* __restrict__ b1,
    const float* __restrict__ W2t, const float* __restrict__ b2,
    const float* __restrict__ W3t, const float* __restrict__ b3,
    const float* __restrict__ log_sigma,
    _Float16* __restrict__ fxh, float* __restrict__ nxs,
    _Float16* __restrict__ fzh, float* __restrict__ nzs)
{
  // xbuf pad 132 (= 4 mod 32 dwords): wave64 float4 reads land 8/bank = LDS min
  __shared__ float xbuf[64*132];  // 64 rows x 128 d, coalesced-staged
  __shared__ float hbuf[64*68];   // 64 rows x 64 h, pad to 68
  __shared__ float nred[64*4];

  const int which = blockIdx.z;   // 0 -> x, 1 -> z
  const int nrows = which ? M_ : N_;
  if (blockIdx.x * 64 >= nrows) return;
  const float* __restrict__ src = which ? z : x;
  _Float16* __restrict__ dsth = which ? fzh : fxh;
  float* __restrict__ dstn = which ? nzs : nxs;

  const int t = threadIdx.x;
  const int lane = t & 63;
  const int wv = __builtin_amdgcn_readfirstlane(t >> 6); // wave id, uniform -> scalar weight loads
  const int k = blockIdx.y;
  const int row0 = blockIdx.x * 64;
  const int row = row0 + lane;
  const int h0 = wv * 16;

  const float* __restrict__ w1 = W1t + k*(D_*H_);
  const float* __restrict__ w2 = W2t + k*(H_*H_);
  const float* __restrict__ w3 = W3t + k*(H_*H_);

  // ---- coalesced stage of the 64x128 fp32 input tile
  {
    const float4* __restrict__ gx = (const float4*)(src + (size_t)row0 * D_);
    #pragma unroll
    for (int it = 0; it < 8; it++) {
      int idx = t + it*256;          // 0..2047 float4s; 32 float4 per row
      int r = idx >> 5, c = idx & 31;
      *(float4*)&xbuf[r*132 + c*4] = gx[idx];
    }
  }
  __syncthreads();

  float acc[16];
  // ---- layer 1: D=128 -> 16 outputs of H
  #pragma unroll
  for (int i=0;i<16;i++) acc[i] = b1[k*H_ + h0 + i];
  #pragma unroll 2
  for (int d4=0; d4<D_/4; d4++) {
    float4 xv = *(const float4*)&xbuf[lane*132 + d4*4];
    const float* wd = w1 + d4*4*H_ + h0;
    #pragma unroll
    for (int i=0;i<16;i++) acc[i] = fmaf(xv.x, wd[i], acc[i]);
    #pragma unroll
    for (int i=0;i<16;i++) acc[i] = fmaf(xv.y, wd[H_+i], acc[i]);
    #pragma unroll
    for (int i=0;i<16;i++) acc[i] = fmaf(xv.z, wd[2*H_+i], acc[i]);
    #pragma unroll
    for (int i=0;i<16;i++) acc[i] = fmaf(xv.w, wd[3*H_+i], acc[i]);
  }
  #pragma unroll
  for (int i=0;i<16;i+=4) {
    float4 v;
    v.x = softplus_f(acc[i+0]); v.y = softplus_f(acc[i+1]);
    v.z = softplus_f(acc[i+2]); v.w = softplus_f(acc[i+3]);
    *(float4*)&hbuf[lane*68 + h0 + i] = v;
  }
  __syncthreads();
  // ---- layer 2
  #pragma unroll
  for (int i=0;i<16;i++) acc[i] = b2[k*H_ + h0 + i];
  #pragma unroll 2
  for (int h4=0; h4<H_/4; h4++) {
    float4 hv = *(const float4*)&hbuf[lane*68 + h4*4];
    const float* wd = w2 + h4*4*H_ + h0;
    #pragma unroll
    for (int i=0;i<16;i++) acc[i] = fmaf(hv.x, wd[i], acc[i]);
    #pragma unroll
    for (int i=0;i<16;i++) acc[i] = fmaf(hv.y, wd[H_+i], acc[i]);
    #pragma unroll
    for (int i=0;i<16;i++) acc[i] = fmaf(hv.z, wd[2*H_+i], acc[i]);
    #pragma unroll
    for (int i=0;i<16;i++) acc[i] = fmaf(hv.w, wd[3*H_+i], acc[i]);
  }
  __syncthreads();  // all reads of h1 done
  #pragma unroll
  for (int i=0;i<16;i+=4) {
    float4 v;
    v.x = softplus_f(acc[i+0]); v.y = softplus_f(acc[i+1]);
    v.z = softplus_f(acc[i+2]); v.w = softplus_f(acc[i+3]);
    *(float4*)&hbuf[lane*68 + h0 + i] = v;
  }
  __syncthreads();
  // ---- layer 3 (no activation)
  #pragma unroll
  for (int i=0;i<16;i++) acc[i] = b3[k*H_ + h0 + i];
  #pragma unroll 2
  for (int h4=0; h4<H_/4; h4++) {
    float4 hv = *(const float4*)&hbuf[lane*68 + h4*4];
    const float* wd = w3 + h4*4*H_ + h0;
    #pragma unroll
    for (int i=0;i<16;i++) acc[i] = fmaf(hv.x, wd[i], acc[i]);
    #pragma unroll
    for (int i=0;i<16;i++) acc[i] = fmaf(hv.y, wd[H_+i], acc[i]);
    #pragma unroll
    for (int i=0;i<16;i++) acc[i] = fmaf(hv.z, wd[2*H_+i], acc[i]);
    #pragma unroll
    for (int i=0;i<16;i++) acc[i] = fmaf(hv.w, wd[3*H_+i], acc[i]);
  }
  // ---- scale by sqrt(c2_k), round to fp16, norms from ROUNDED values
  float lsv = log_sigma[k];
  float inv2sig = 0.5f * exp2f(-lsv * 3.32192809489f);  // 1/(2*10^ls)
  float c2 = inv2sig * 1.44269504089f;                  // * log2(e)
  float s = sqrtf(c2);
  half8 u0, u1;
  float nsum = 0.f;
  #pragma unroll
  for (int i=0;i<8;i++) {
    _Float16 v = (_Float16)(s * acc[i]);
    u0[i] = v; float f = (float)v; nsum = fmaf(f, f, nsum);
  }
  #pragma unroll
  for (int i=0;i<8;i++) {
    _Float16 v = (_Float16)(s * acc[8+i]);
    u1[i] = v; float f = (float)v; nsum = fmaf(f, f, nsum);
  }
  // fragment-native store: chunk c = row/16, tile [ks][fq][fr][8].
  // wave wv covers h0..h0+15 -> ks0 = wv>>1, fq0 = (wv&1)*2 (u0), fq0+1 (u1).
  // 16 consecutive lanes -> 256 B contiguous (full lines), 4 chunks/instr.
  {
    const int c16 = row >> 4;
    const int frp = row & 15;
    const int ks0 = wv >> 1;
    const int fq0 = (wv & 1) * 2;
    _Float16* dp = dsth + ((size_t)(k*(nrows >> 4) + c16))*1024
                        + ks0*512 + fq0*128 + frp*8;
    *(half8*)dp = u0;
    *(half8*)(dp + 128) = u1;   // next fq
  }
  nred[lane*4 + wv] = nsum;
  __syncthreads();
  if (t < 64) {
    float v = nred[t*4+0] + nred[t*4+1] + nred[t*4+2] + nred[t*4+3];
    dstn[(size_t)k*nrows + row] = v;
  }
}

// ---------------- main: barrier-free MFMA dot + exp + weighted sum ----------------
// No LDS, no __syncthreads. Fragments load straight from L2-resident fxh/fzh
// (fragment-native layout -> fully-coalesced dwordx4 loads). 4 waves = 2x2 of
// 64x64; ~145 VGPR under the 170-cap of (256,3) -> 12 waves/CU free-running.
__global__ __launch_bounds__(256, 3) void dkef_main(
    const _Float16* __restrict__ fxh, const _Float16* __restrict__ fzh,
    const float* __restrict__ nxs, const float* __restrict__ nzs,
    const float* __restrict__ kw, float* __restrict__ out)
{
  const int t = threadIdx.x;
  const int lane = t & 63;
  const int wv = t >> 6;           // 0..3

  // XCD-chunked swizzle (bijective: 4096 blocks = 8 * 512): per-XCD working
  // set = fzh (1.6MB) + fxh n-chunk (0.8MB) < 4MiB L2.
  const int NTM = M_/128;                         // 32
  const int orig = blockIdx.y * NTM + blockIdx.x; // flatten, x fastest
  const int swz = (orig & 7) * ((NTM*(N_/128)) >> 3) + (orig >> 3);
  const int m0 = (swz % NTM) * 128;
  const int n0 = (swz / NTM) * 128;

  // softmax over kernel_weights (3 values), computed redundantly per thread
  float k0 = kw[0], k1 = kw[1], k2 = kw[2];
  float mx = fmaxf(k0, fmaxf(k1, k2));
  float e0 = exp2f((k0 - mx) * 1.44269504089f);
  float e1 = exp2f((k1 - mx) * 1.44269504089f);
  float e2 = exp2f((k2 - mx) * 1.44269504089f);
  float winv = 1.0f / (e0 + e1 + e2);
  float wk3[3] = {e0 * winv, e1 * winv, e2 * winv};

  const int wa = (wv >> 1) * 64;   // n-half within block tile
  const int wb = (wv & 1) * 64;    // m-half
  const int fr = lane & 15;        // frag row/col
  const int fq = lane >> 4;        // quad

  floatx4 oacc[4][4] = {};

  const int cn = (n0 + wa) >> 4;   // 16-row chunk indices
  const int cm = (m0 + wb) >> 4;

  for (int k = 0; k < K_; k++) {
    // fragment loads: 1024 B contiguous per instr (8 full lines), L2-hot
    const _Float16* pa = fxh + ((size_t)(k*(N_/16) + cn))*1024 + fq*128 + fr*8;
    const _Float16* pb = fzh + ((size_t)(k*(M_/16) + cm))*1024 + fq*128 + fr*8;
    half8 bf[4][2];
    #pragma unroll
    for (int j = 0; j < 4; j++) {
      bf[j][0] = *(const half8*)(pb + j*1024);
      bf[j][1] = *(const half8*)(pb + j*1024 + 512);
    }
    floatx4 nx4[4];
    float nzv[4];
    #pragma unroll
    for (int i = 0; i < 4; i++)
      nx4[i] = *(const floatx4*)&nxs[(size_t)k*N_ + n0 + wa + i*16 + fq*4];
    #pragma unroll
    for (int j = 0; j < 4; j++)
      nzv[j] = nzs[(size_t)k*M_ + m0 + wb + j*16 + fr];

    float wkv = wk3[k];
    #pragma unroll
    for (int i = 0; i < 4; i++) {
      half8 a0 = *(const half8*)(pa + i*1024);
      half8 a1 = *(const half8*)(pa + i*1024 + 512);
      #pragma unroll
      for (int j = 0; j < 4; j++) {
        floatx4 d = {};
        d = __builtin_amdgcn_mfma_f32_16x16x32_f16(a0, bf[j][0], d, 0, 0, 0);
        d = __builtin_amdgcn_mfma_f32_16x16x32_f16(a1, bf[j][1], d, 0, 0, 0);
        // epilogue fused per tile: out += w_k * 2^min(2*dot - (nx+nz), 0)
        #pragma unroll
        for (int r = 0; r < 4; r++) {
          float sm = nx4[i][r] + nzv[j];
          float e = fmaf(2.0f, d[r], -sm);
          e = fminf(e, 0.0f);
          oacc[i][j][r] = fmaf(wkv, exp2f(e), oacc[i][j][r]);
        }
      }
    }
  }

  // store 128x128 tile; nontemporal: out is write-once streaming.
  #pragma unroll
  for (int i = 0; i < 4; i++) {
    #pragma unroll
    for (int r = 0; r < 4; r++) {
      size_t rowg = (size_t)(n0 + wa + i*16 + fq*4 + r);
      float* orow = out + rowg * M_ + m0 + wb + fr;
      #pragma unroll
      for (int j = 0; j < 4; j++)
        __builtin_nontemporal_store(oacc[i][j][r], &orow[j*16]);
    }
  }
}

extern "C" void kernel_launch(void* const* d_in, const int* in_sizes, int n_in,
                              void* d_out, int out_size, void* d_ws, size_t ws_size,
                              hipStream_t stream) {
  const float* x  = (const float*)d_in[0];
  const float* z  = (const float*)d_in[1];
  const float* W1 = (const float*)d_in[2];
  const float* b1 = (const float*)d_in[3];
  const float* W2 = (const float*)d_in[4];
  const float* b2 = (const float*)d_in[5];
  const float* W3 = (const float*)d_in[6];
  const float* b3 = (const float*)d_in[7];
  const float* ls = (const float*)d_in[8];
  const float* kw = (const float*)d_in[9];
  float* out = (float*)d_out;

  char* ws = (char*)d_ws;
  _Float16* fxh = (_Float16*)(ws + OFF_FXH);
  _Float16* fzh = (_Float16*)(ws + OFF_FZH);
  float* nxs = (float*)(ws + OFF_NXS);
  float* nzs = (float*)(ws + OFF_NZS);
  float* W1t = (float*)(ws + OFF_W1T);
  float* W2t = (float*)(ws + OFF_W2T);
  float* W3t = (float*)(ws + OFF_W3T);

  hipLaunchKernelGGL(transpose_w, dim3((K_*H_*D_ + 255)/256), dim3(256), 0, stream,
                     W1, W2, W3, W1t, W2t, W3t);
  hipLaunchKernelGGL(phi_kernel, dim3(N_/64, K_, 2), dim3(256), 0, stream,
                     x, z, W1t, b1, W2t, b2, W3t, b3, ls, fxh, nxs, fzh, nzs);
  hipLaunchKernelGGL(dkef_main, dim3(M_/128, N_/128), dim3(256), 0, stream,
                     fxh, fzh, nxs, nzs, kw, out);
}

// Round 4
// 356.340 us; speedup vs baseline: 1.0797x; 1.0039x over previous
//
#include <hip/hip_runtime.h>

typedef _Float16 half8 __attribute__((ext_vector_type(8)));
typedef float floatx4 __attribute__((ext_vector_type(4)));

#define K_ 3
#define N_ 16384
#define M_ 4096
#define D_ 128
#define H_ 64

// workspace layout (bytes)
#define OFF_FXH 0
#define SZ_FXH (K_*N_*H_*2)
#define OFF_FZH (OFF_FXH + SZ_FXH)
#define SZ_FZH (K_*M_*H_*2)
#define OFF_NXS (OFF_FZH + SZ_FZH)
#define SZ_NXS (K_*N_*4)
#define OFF_NZS (OFF_NXS + SZ_NXS)
#define SZ_NZS (K_*M_*4)
#define OFF_W1T (OFF_NZS + SZ_NZS)
#define SZ_W1T (K_*D_*H_*4)
#define OFF_W2T (OFF_W1T + SZ_W1T)
#define SZ_W2T (K_*H_*H_*4)
#define OFF_W3T (OFF_W2T + SZ_W2T)

// fxh/fzh are stored FRAGMENT-NATIVE: for each k and 16-row chunk c,
// a 1024-half (2 KB) tile laid out [ks(2)][fq(4)][fr(16)][e(8)] where
// element (row, h) lives at ks=h/32, fq=(h%32)/8, fr=row%16, e=h%8.
// A dkef MFMA fragment load (lane&15=fr, lane>>4=fq) is then
// 64 lanes x 16 B = 1024 B CONTIGUOUS -> 8 full cache lines.

// ---------------- weight transpose (tiny) ----------------
__global__ void transpose_w(const float* __restrict__ W1,
                            const float* __restrict__ W2,
                            const float* __restrict__ W3,
                            float* __restrict__ W1t,
                            float* __restrict__ W2t,
                            float* __restrict__ W3t) {
  int idx = blockIdx.x * 256 + threadIdx.x;
  if (idx < K_*H_*D_) {   // W1[k][h][d] -> W1t[k][d][h]
    int k = idx / (H_*D_); int r = idx % (H_*D_);
    int h = r / D_; int d = r % D_;
    W1t[k*(D_*H_) + d*H_ + h] = W1[idx];
  }
  if (idx < K_*H_*H_) {   // W2[k][g][h] -> W2t[k][h][g]; same for W3
    int k = idx / (H_*H_); int r = idx % (H_*H_);
    int g = r / H_; int h = r % H_;
    W2t[k*(H_*H_) + h*H_ + g] = W2[idx];
    W3t[k*(H_*H_) + h*H_ + g] = W3[idx];
  }
}

// ---------------- phi: fused 3-layer MLP, fp32, scale + fp16 round + norms ----------------
__device__ __forceinline__ float softplus_f(float x) {
  float p = exp2f(x * 1.44269504089f);
  float r = 0.693147180560f * log2f(1.0f + p);
  return (x > 20.0f) ? x : r;
}

__global__ __launch_bounds__(256) void phi_kernel(
    const float* __restrict__ x, const float* __restrict__ z,
    const float* __restrict__ W1t, const float* __restrict__ b1,
    const float* __restrict__ W2t, const float* __restrict__ b2,
    const float* __restrict__ W3t, const float* __restrict__ b3,
    const float* __restrict__ log_sigma,
    _Float16* __restrict__ fxh, float* __restrict__ nxs,
    _Float16* __restrict__ fzh, float* __restrict__ nzs)
{
  // xbuf pad 132 (= 4 mod 32 dwords): wave64 float4 reads land 8/bank = LDS min
  __shared__ float xbuf[64*132];  // 64 rows x 128 d, coalesced-staged
  __shared__ float hbuf[64*68];   // 64 rows x 64 h, pad to 68
  __shared__ float nred[64*4];

  const int which = blockIdx.z;   // 0 -> x, 1 -> z
  const int nrows = which ? M_ : N_;
  if (blockIdx.x * 64 >= nrows) return;
  const float* __restrict__ src = which ? z : x;
  _Float16* __restrict__ dsth = which ? fzh : fxh;
  float* __restrict__ dstn = which ? nzs : nxs;

  const int t = threadIdx.x;
  const int lane = t & 63;
  const int wv = __builtin_amdgcn_readfirstlane(t >> 6); // wave id, uniform -> scalar weight loads
  const int k = blockIdx.y;
  const int row0 = blockIdx.x * 64;
  const int row = row0 + lane;
  const int h0 = wv * 16;

  const float* __restrict__ w1 = W1t + k*(D_*H_);
  const float* __restrict__ w2 = W2t + k*(H_*H_);
  const float* __restrict__ w3 = W3t + k*(H_*H_);

  // ---- coalesced stage of the 64x128 fp32 input tile
  {
    const float4* __restrict__ gx = (const float4*)(src + (size_t)row0 * D_);
    #pragma unroll
    for (int it = 0; it < 8; it++) {
      int idx = t + it*256;          // 0..2047 float4s; 32 float4 per row
      int r = idx >> 5, c = idx & 31;
      *(float4*)&xbuf[r*132 + c*4] = gx[idx];
    }
  }
  __syncthreads();

  float acc[16];
  // ---- layer 1: D=128 -> 16 outputs of H
  #pragma unroll
  for (int i=0;i<16;i++) acc[i] = b1[k*H_ + h0 + i];
  #pragma unroll 2
  for (int d4=0; d4<D_/4; d4++) {
    float4 xv = *(const float4*)&xbuf[lane*132 + d4*4];
    const float* wd = w1 + d4*4*H_ + h0;
    #pragma unroll
    for (int i=0;i<16;i++) acc[i] = fmaf(xv.x, wd[i], acc[i]);
    #pragma unroll
    for (int i=0;i<16;i++) acc[i] = fmaf(xv.y, wd[H_+i], acc[i]);
    #pragma unroll
    for (int i=0;i<16;i++) acc[i] = fmaf(xv.z, wd[2*H_+i], acc[i]);
    #pragma unroll
    for (int i=0;i<16;i++) acc[i] = fmaf(xv.w, wd[3*H_+i], acc[i]);
  }
  #pragma unroll
  for (int i=0;i<16;i+=4) {
    float4 v;
    v.x = softplus_f(acc[i+0]); v.y = softplus_f(acc[i+1]);
    v.z = softplus_f(acc[i+2]); v.w = softplus_f(acc[i+3]);
    *(float4*)&hbuf[lane*68 + h0 + i] = v;
  }
  __syncthreads();
  // ---- layer 2
  #pragma unroll
  for (int i=0;i<16;i++) acc[i] = b2[k*H_ + h0 + i];
  #pragma unroll 2
  for (int h4=0; h4<H_/4; h4++) {
    float4 hv = *(const float4*)&hbuf[lane*68 + h4*4];
    const float* wd = w2 + h4*4*H_ + h0;
    #pragma unroll
    for (int i=0;i<16;i++) acc[i] = fmaf(hv.x, wd[i], acc[i]);
    #pragma unroll
    for (int i=0;i<16;i++) acc[i] = fmaf(hv.y, wd[H_+i], acc[i]);
    #pragma unroll
    for (int i=0;i<16;i++) acc[i] = fmaf(hv.z, wd[2*H_+i], acc[i]);
    #pragma unroll
    for (int i=0;i<16;i++) acc[i] = fmaf(hv.w, wd[3*H_+i], acc[i]);
  }
  __syncthreads();  // all reads of h1 done
  #pragma unroll
  for (int i=0;i<16;i+=4) {
    float4 v;
    v.x = softplus_f(acc[i+0]); v.y = softplus_f(acc[i+1]);
    v.z = softplus_f(acc[i+2]); v.w = softplus_f(acc[i+3]);
    *(float4*)&hbuf[lane*68 + h0 + i] = v;
  }
  __syncthreads();
  // ---- layer 3 (no activation)
  #pragma unroll
  for (int i=0;i<16;i++) acc[i] = b3[k*H_ + h0 + i];
  #pragma unroll 2
  for (int h4=0; h4<H_/4; h4++) {
    float4 hv = *(const float4*)&hbuf[lane*68 + h4*4];
    const float* wd = w3 + h4*4*H_ + h0;
    #pragma unroll
    for (int i=0;i<16;i++) acc[i] = fmaf(hv.x, wd[i], acc[i]);
    #pragma unroll
    for (int i=0;i<16;i++) acc[i] = fmaf(hv.y, wd[H_+i], acc[i]);
    #pragma unroll
    for (int i=0;i<16;i++) acc[i] = fmaf(hv.z, wd[2*H_+i], acc[i]);
    #pragma unroll
    for (int i=0;i<16;i++) acc[i] = fmaf(hv.w, wd[3*H_+i], acc[i]);
  }
  // ---- scale by sqrt(c2_k), round to fp16, norms from ROUNDED values
  float lsv = log_sigma[k];
  float inv2sig = 0.5f * exp2f(-lsv * 3.32192809489f);  // 1/(2*10^ls)
  float c2 = inv2sig * 1.44269504089f;                  // * log2(e)
  float s = sqrtf(c2);
  half8 u0, u1;
  float nsum = 0.f;
  #pragma unroll
  for (int i=0;i<8;i++) {
    _Float16 v = (_Float16)(s * acc[i]);
    u0[i] = v; float f = (float)v; nsum = fmaf(f, f, nsum);
  }
  #pragma unroll
  for (int i=0;i<8;i++) {
    _Float16 v = (_Float16)(s * acc[8+i]);
    u1[i] = v; float f = (float)v; nsum = fmaf(f, f, nsum);
  }
  // fragment-native store: chunk c = row/16, tile [ks][fq][fr][8].
  {
    const int c16 = row >> 4;
    const int frp = row & 15;
    const int ks0 = wv >> 1;
    const int fq0 = (wv & 1) * 2;
    _Float16* dp = dsth + ((size_t)(k*(nrows >> 4) + c16))*1024
                        + ks0*512 + fq0*128 + frp*8;
    *(half8*)dp = u0;
    *(half8*)(dp + 128) = u1;   // next fq
  }
  nred[lane*4 + wv] = nsum;
  __syncthreads();
  if (t < 64) {
    float v = nred[t*4+0] + nred[t*4+1] + nred[t*4+2] + nred[t*4+3];
    dstn[(size_t)k*nrows + row] = v;
  }
}

// ---------------- main: barrier-free MFMA dot + exp + weighted sum ----------------
// No __syncthreads. Fragments load straight from L2-resident fxh/fzh
// (fragment-native layout -> fully-coalesced dwordx4 loads). Epilogue stores
// are staged through a PER-WAVE LDS tile (wave-synchronous, no barrier) so
// every global store is a full-line 256B-contiguous dwordx4 -- the previous
// per-dword nontemporal stores wrote 64B half-lines, risking 2x HBM write
// amplification under the nt hint.
__global__ __launch_bounds__(256, 3) void dkef_main(
    const _Float16* __restrict__ fxh, const _Float16* __restrict__ fzh,
    const float* __restrict__ nxs, const float* __restrict__ nzs,
    const float* __restrict__ kw, float* __restrict__ out)
{
  // per-wave 16x64 staging tile, row stride 68 floats (272B, 16B-aligned;
  // fq-groups land 16 banks apart -> 2-way = free)
  __shared__ __align__(16) float obuf[4][16*68 + 4];

  const int t = threadIdx.x;
  const int lane = t & 63;
  const int wv = t >> 6;           // 0..3

  // XCD-chunked swizzle (bijective: 4096 blocks = 8 * 512): per-XCD working
  // set = fzh (1.6MB) + fxh n-chunk (0.8MB) < 4MiB L2.
  const int NTM = M_/128;                         // 32
  const int orig = blockIdx.y * NTM + blockIdx.x; // flatten, x fastest
  const int swz = (orig & 7) * ((NTM*(N_/128)) >> 3) + (orig >> 3);
  const int m0 = (swz % NTM) * 128;
  const int n0 = (swz / NTM) * 128;

  // softmax over kernel_weights (3 values), computed redundantly per thread
  float k0 = kw[0], k1 = kw[1], k2 = kw[2];
  float mx = fmaxf(k0, fmaxf(k1, k2));
  float e0 = exp2f((k0 - mx) * 1.44269504089f);
  float e1 = exp2f((k1 - mx) * 1.44269504089f);
  float e2 = exp2f((k2 - mx) * 1.44269504089f);
  float winv = 1.0f / (e0 + e1 + e2);
  float wk3[3] = {e0 * winv, e1 * winv, e2 * winv};

  const int wa = (wv >> 1) * 64;   // n-half within block tile
  const int wb = (wv & 1) * 64;    // m-half
  const int fr = lane & 15;        // frag row/col
  const int fq = lane >> 4;        // quad

  floatx4 oacc[4][4] = {};

  const int cn = (n0 + wa) >> 4;   // 16-row chunk indices
  const int cm = (m0 + wb) >> 4;

  for (int k = 0; k < K_; k++) {
    // fragment loads: 1024 B contiguous per instr (8 full lines), L2-hot
    const _Float16* pa = fxh + ((size_t)(k*(N_/16) + cn))*1024 + fq*128 + fr*8;
    const _Float16* pb = fzh + ((size_t)(k*(M_/16) + cm))*1024 + fq*128 + fr*8;
    half8 bf[4][2];
    #pragma unroll
    for (int j = 0; j < 4; j++) {
      bf[j][0] = *(const half8*)(pb + j*1024);
      bf[j][1] = *(const half8*)(pb + j*1024 + 512);
    }
    floatx4 nx4[4];
    float nzv[4];
    #pragma unroll
    for (int i = 0; i < 4; i++)
      nx4[i] = *(const floatx4*)&nxs[(size_t)k*N_ + n0 + wa + i*16 + fq*4];
    #pragma unroll
    for (int j = 0; j < 4; j++)
      nzv[j] = nzs[(size_t)k*M_ + m0 + wb + j*16 + fr];

    float wkv = wk3[k];
    #pragma unroll
    for (int i = 0; i < 4; i++) {
      half8 a0 = *(const half8*)(pa + i*1024);
      half8 a1 = *(const half8*)(pa + i*1024 + 512);
      #pragma unroll
      for (int j = 0; j < 4; j++) {
        floatx4 d = {};
        d = __builtin_amdgcn_mfma_f32_16x16x32_f16(a0, bf[j][0], d, 0, 0, 0);
        d = __builtin_amdgcn_mfma_f32_16x16x32_f16(a1, bf[j][1], d, 0, 0, 0);
        // epilogue fused per tile: out += w_k * 2^min(2*dot - (nx+nz), 0)
        #pragma unroll
        for (int r = 0; r < 4; r++) {
          float sm = nx4[i][r] + nzv[j];
          float e = fmaf(2.0f, d[r], -sm);
          e = fminf(e, 0.0f);
          oacc[i][j][r] = fmaf(wkv, exp2f(e), oacc[i][j][r]);
        }
      }
    }
  }

  // store 128x128 tile. Per wave, per 16-row slice: scatter accumulators into
  // the wave-private LDS tile, read back row-contiguous float4, store as
  // full-line dwordx4 (4 rows x 256B = 8 full lines per instr). Intra-wave
  // LDS dependence -> compiler-inserted lgkmcnt waits; no barrier needed.
  float* ob = &obuf[wv][0];
  #pragma unroll
  for (int i = 0; i < 4; i++) {
    #pragma unroll
    for (int j = 0; j < 4; j++)
      #pragma unroll
      for (int r = 0; r < 4; r++)
        ob[(fq*4 + r)*68 + j*16 + fr] = oacc[i][j][r];
    #pragma unroll
    for (int s = 0; s < 4; s++) {
      floatx4 v = *(const floatx4*)&ob[(s*4 + fq)*68 + fr*4];
      size_t rowg = (size_t)(n0 + wa + i*16 + s*4 + fq);
      float* orow = out + rowg * M_ + m0 + wb + fr*4;
      __builtin_nontemporal_store(v, (floatx4*)orow);
    }
  }
}

extern "C" void kernel_launch(void* const* d_in, const int* in_sizes, int n_in,
                              void* d_out, int out_size, void* d_ws, size_t ws_size,
                              hipStream_t stream) {
  const float* x  = (const float*)d_in[0];
  const float* z  = (const float*)d_in[1];
  const float* W1 = (const float*)d_in[2];
  const float* b1 = (const float*)d_in[3];
  const float* W2 = (const float*)d_in[4];
  const float* b2 = (const float*)d_in[5];
  const float* W3 = (const float*)d_in[6];
  const float* b3 = (const float*)d_in[7];
  const float* ls = (const float*)d_in[8];
  const float* kw = (const float*)d_in[9];
  float* out = (float*)d_out;

  char* ws = (char*)d_ws;
  _Float16* fxh = (_Float16*)(ws + OFF_FXH);
  _Float16* fzh = (_Float16*)(ws + OFF_FZH);
  float* nxs = (float*)(ws + OFF_NXS);
  float* nzs = (float*)(ws + OFF_NZS);
  float* W1t = (float*)(ws + OFF_W1T);
  float* W2t = (float*)(ws + OFF_W2T);
  float* W3t = (float*)(ws + OFF_W3T);

  hipLaunchKernelGGL(transpose_w, dim3((K_*H_*D_ + 255)/256), dim3(256), 0, stream,
                     W1, W2, W3, W1t, W2t, W3t);
  hipLaunchKernelGGL(phi_kernel, dim3(N_/64, K_, 2), dim3(256), 0, stream,
                     x, z, W1t, b1, W2t, b2, W3t, b3, ls, fxh, nxs, fzh, nzs);
  hipLaunchKernelGGL(dkef_main, dim3(M_/128, N_/128), dim3(256), 0, stream,
                     fxh, fzh, nxs, nzs, kw, out);
}